// Round 12
// baseline (1262.197 us; speedup 1.0000x reference)
//
#include <hip/hip_runtime.h>
#include <math.h>

// Sliced Wasserstein-2: for each (b,c,p): W2^2 = mean_i (sort(X@theta_p) - sort(Y@theta_p))^2
// loss = mean_{b,c} sqrt(mean_p W2^2)
//
// R12: R11's fusion reintroduced spill (VGPR 64, WRITE 371MB vs 205MB staged):
// two inlined sort_dist bodies let the scheduler pipeline across the phase
// boundary (holds phase-1 stores live through phase-2) and double code size.
// Fix: phase loop (#pragma unroll 1) -> ONE sort_dist instantiation, uniform
// store/reduce branch; loop-carried state is just v[32]+acc.

namespace {
constexpr int Bb = 8, Cc = 4, Nn = 32768, Pp = 50;
constexpr int THREADS = 1024;
constexpr int VPT = 32;                    // values per thread
constexpr int SLICES = Bb * Cc * Pp;       // 1600
constexpr size_t W2_BYTES = 8192;          // w2[1600] rounded up
constexpr int LDS_FLOATS = Nn + (Nn >> 5); // padded buffer: 33792 floats
}

__device__ __forceinline__ void ce(float& a, float& b, bool up) {
  float lo = fminf(a, b);
  float hi = fmaxf(a, b);
  a = up ? lo : hi;
  b = up ? hi : lo;
}

// 2-VALU compare-select CE: keepMin ? min(v,o) : max(v,o); ties resolve
// consistently on both partners (multiset preserved).
__device__ __forceinline__ float sel_ce(float v, float o, bool keepMin) {
  return ((o < v) != keepMin) ? v : o;
}

__device__ __forceinline__ float dpp_xor(float x, int ctrl_sel) {
  // 0xB1 = quad_perm(1,0,3,2) = xor1; 0x4E = quad_perm(2,3,0,1) = xor2
  int i = ctrl_sel == 0xB1
    ? __builtin_amdgcn_update_dpp(0, __float_as_int(x), 0xB1, 0xF, 0xF, true)
    : __builtin_amdgcn_update_dpp(0, __float_as_int(x), 0x4E, 0xF, 0xF, true);
  return __int_as_float(i);
}

// cross-lane CE stage with xor-mask M (M=1,2 via DPP; M>=4 via ds_bpermute)
template<int M>
__device__ __forceinline__ void stage_xlane(float v[VPT], int tid, bool up) {
  const bool keepMin = (up == ((tid & M) == 0));
  if constexpr (M == 1 || M == 2) {
    constexpr int ctrl = (M == 1) ? 0xB1 : 0x4E;
#pragma unroll
    for (int r = 0; r < VPT; r++) {
      float o = dpp_xor(v[r], ctrl);
      v[r] = sel_ce(v[r], o, keepMin);
    }
  } else {
    const int addr = (((tid & 63) ^ M) << 2);
#pragma unroll
    for (int r = 0; r < VPT; r++) {
      float o = __int_as_float(
          __builtin_amdgcn_ds_bpermute(addr, __float_as_int(v[r])));
      v[r] = sel_ce(v[r], o, keepMin);
    }
  }
}

// 5-stage in-register network on the reg-index bits (j=16..1), direction
// uniform per thread via sign-flip trick.
__device__ __forceinline__ void tail_inreg(float v[VPT], bool up) {
  const unsigned flip = up ? 0u : 0x80000000u;
#pragma unroll
  for (int r = 0; r < VPT; r++)
    v[r] = __int_as_float(__float_as_int(v[r]) ^ flip);
#pragma unroll
  for (int j = 16; j > 0; j >>= 1) {
#pragma unroll
    for (int r = 0; r < VPT; r++) {
      if (!(r & j)) {
        float a = v[r], b = v[r | j];
        v[r] = fminf(a, b);
        v[r | j] = fmaxf(a, b);
      }
    }
  }
#pragma unroll
  for (int r = 0; r < VPT; r++)
    v[r] = __int_as_float(__float_as_int(v[r]) ^ flip);
}

// wave-local cross stages (m = MTOP..1) + tail, for merge k = 2^A (A<=12)
template<int A, int MTOP>
__device__ __forceinline__ void wave_stages_and_tail(float v[VPT], int tid) {
  const bool up = ((tid & (1 << (A - 5))) == 0);
  if constexpr (MTOP >= 32) stage_xlane<32>(v, tid, up);
  if constexpr (MTOP >= 16) stage_xlane<16>(v, tid, up);
  if constexpr (MTOP >= 8)  stage_xlane<8>(v, tid, up);
  if constexpr (MTOP >= 4)  stage_xlane<4>(v, tid, up);
  if constexpr (MTOP >= 2)  stage_xlane<2>(v, tid, up);
  if constexpr (MTOP >= 1)  stage_xlane<1>(v, tid, up);
  tail_inreg(v, up);
}

// LDS-exchange stage (wave-crossing xor-mask m on tid), column layout
__device__ __forceinline__ void stage_lds(float v[VPT], float* s, int tid,
                                          int m, bool up) {
  const bool keepMin = (up == ((tid & m) == 0));
  __syncthreads();                        // prior users of s must finish
#pragma unroll
  for (int r = 0; r < VPT; r++) s[r * THREADS + tid] = v[r];
  __syncthreads();
  const int pt = tid ^ m;
#pragma unroll
  for (int r = 0; r < VPT; r++) {
    float o = s[r * THREADS + pt];
    v[r] = sel_ce(v[r], o, keepMin);
  }
}

// Merge k=2^A (A=13..15) entirely in-register via three layouts:
//  L0: i = tid<<5 | r        (reg = i[4:0])
//  L2: i = r2<<10 | tid      (reg = i[14:10]) -> stages b(A-1)..b10
//  L3: i = tid[9:5]<<10 | r3<<5 | tid[4:0] (reg = i[9:5]) -> stages b9..b5
// Caller finishes with tail_inreg in L0 (stages b4..b0).
// Padded addressing Adr(i) = i + (i>>5): every access <=2-way (free).
template<int A>
__device__ __forceinline__ void merge_high3(float v[VPT], float* s, int tid) {
  const int base = tid * VPT;
  // ---- L0 -> L2 ----
  __syncthreads();                      // prior users of s must finish
#pragma unroll
  for (int r = 0; r < VPT; r++) { int i = base + r; s[i + (i >> 5)] = v[r]; }
  __syncthreads();
#pragma unroll
  for (int r2 = 0; r2 < VPT; r2++) { int i = (r2 << 10) | tid; v[r2] = s[i + (i >> 5)]; }
  // ---- stages b(A-1)..b10 on reg bits, compile-time directions ----
#pragma unroll
  for (int bb = A - 11; bb >= 0; bb--) {
    const int j = 1 << bb;
#pragma unroll
    for (int r2 = 0; r2 < VPT; r2++) {
      if (!(r2 & j)) {
        bool upv = (A == 15) ? true : (((r2 >> (A - 10)) & 1) == 0);
        ce(v[r2], v[r2 | j], upv);
      }
    }
  }
  // ---- L2 -> L3 (rewrite own L2 slots: no barrier before write) ----
#pragma unroll
  for (int r2 = 0; r2 < VPT; r2++) { int i = (r2 << 10) | tid; s[i + (i >> 5)] = v[r2]; }
  __syncthreads();
  const int hi = (tid >> 5) << 10;      // tid[9:5] -> i[14:10]
  const int lo = tid & 31;              // tid[4:0] -> i[4:0]
#pragma unroll
  for (int r3 = 0; r3 < VPT; r3++) { int i = hi | (r3 << 5) | lo; v[r3] = s[i + (i >> 5)]; }
  // ---- stages b9..b5: direction = bit A of i = tid bit (A-5), thread-uniform ----
  const bool up = (A == 15) ? true : ((tid & (1 << (A - 5))) == 0);
  tail_inreg(v, up);
  // ---- L3 -> L0 (rewrite own L3 slots: no barrier before write) ----
#pragma unroll
  for (int r3 = 0; r3 < VPT; r3++) { int i = hi | (r3 << 5) | lo; s[i + (i >> 5)] = v[r3]; }
  __syncthreads();
#pragma unroll
  for (int r = 0; r < VPT; r++) { int i = base + r; v[r] = s[i + (i >> 5)]; }
}

// Full distributed bitonic sort: rank of v[r] on thread tid is tid*32 + r.
__device__ __forceinline__ void sort_dist(float v[VPT], float* s, int tid) {
  // merges a=1..4 (k=2..16): in-register, compile-time directions
#pragma unroll
  for (int k = 2; k <= 16; k <<= 1) {
#pragma unroll
    for (int j = k >> 1; j > 0; j >>= 1) {
#pragma unroll
      for (int r = 0; r < VPT; r++)
        if (!(r & j)) ce(v[r], v[r | j], (r & k) == 0);
    }
  }
  // a=5 (k=32): dir = tid bit0, all stages in-register
  tail_inreg(v, (tid & 1) == 0);
  // a=6..11: wave-local exchanges + tail
  wave_stages_and_tail<6, 1>(v, tid);
  wave_stages_and_tail<7, 2>(v, tid);
  wave_stages_and_tail<8, 4>(v, tid);
  wave_stages_and_tail<9, 8>(v, tid);
  wave_stages_and_tail<10, 16>(v, tid);
  wave_stages_and_tail<11, 32>(v, tid);
  // a=12: one wave-crossing stage (m=64), then wave-local
  stage_lds(v, s, tid, 64, (tid & 128) == 0);
  wave_stages_and_tail<12, 32>(v, tid);
  // a=13..15: three-layout merges (all stages in-register) + L0 tail
  merge_high3<13>(v, s, tid);
  tail_inreg(v, (tid & 256) == 0);
  merge_high3<14>(v, s, tid);
  tail_inreg(v, (tid & 512) == 0);
  merge_high3<15>(v, s, tid);
  tail_inreg(v, true);
}

__device__ __forceinline__ void project_slice(const float4* base, float t0, float t1,
                                              int tid, float v[VPT]) {
#pragma unroll
  for (int q = 0; q < VPT / 2; q++) {
    float4 u = base[tid * (VPT / 2) + q];
    v[2 * q]     = fmaf(u.x, t0, u.y * t1);
    v[2 * q + 1] = fmaf(u.z, t0, u.w * t1);
  }
}

// ---- fused kernel: phase 0 = sort X -> stage; phase 1 = sort Y -> reduce ----
extern "C" __global__ void __launch_bounds__(THREADS)
swd_fused(const float* __restrict__ x, const float* __restrict__ y,
          const float* __restrict__ proj, float* __restrict__ xs,
          float* __restrict__ w2, int slice_base) {
  extern __shared__ float s[];
  __shared__ float wsum[THREADS / 64];
  const int slice = slice_base + blockIdx.x;
  const int p  = slice % Pp;
  const int bc = slice / Pp;
  const int tid = threadIdx.x;
  const float t0 = proj[2 * p];
  const float t1 = proj[2 * p + 1];
  const float4* xsrc = (const float4*)(x + (size_t)bc * Nn * 2);
  const float4* ysrc = (const float4*)(y + (size_t)bc * Nn * 2);
  float4* xsp = (float4*)(xs + (size_t)blockIdx.x * Nn + tid * VPT);

  float v[VPT];
  float acc = 0.f;
#pragma unroll 1
  for (int phase = 0; phase < 2; phase++) {
    project_slice(phase ? ysrc : xsrc, t0, t1, tid, v);
    sort_dist(v, s, tid);
    if (phase == 0) {
      // park sorted X in global scratch (own 128B range, coalesced)
#pragma unroll
      for (int q = 0; q < VPT / 4; q++)
        xsp[q] = make_float4(v[4 * q], v[4 * q + 1], v[4 * q + 2], v[4 * q + 3]);
    } else {
      // same thread reads back exactly what it wrote: program order suffices
#pragma unroll
      for (int q = 0; q < VPT / 4; q++) {
        float4 u = xsp[q];
        float d0 = u.x - v[4 * q];
        float d1 = u.y - v[4 * q + 1];
        float d2 = u.z - v[4 * q + 2];
        float d3 = u.w - v[4 * q + 3];
        acc = fmaf(d0, d0, acc);
        acc = fmaf(d1, d1, acc);
        acc = fmaf(d2, d2, acc);
        acc = fmaf(d3, d3, acc);
      }
    }
  }

#pragma unroll
  for (int off = 32; off > 0; off >>= 1)
    acc += __shfl_down(acc, off, 64);
  if ((tid & 63) == 0) wsum[tid >> 6] = acc;
  __syncthreads();
  if (tid == 0) {
    float t = 0.f;
#pragma unroll
    for (int w = 0; w < THREADS / 64; w++) t += wsum[w];
    w2[slice] = t * (1.0f / Nn);
  }
}

extern "C" __global__ void swd_final(const float* __restrict__ w2,
                                     float* __restrict__ out) {
  __shared__ float sred[Bb * Cc];
  int t = threadIdx.x;
  if (t < Bb * Cc) {
    float sum = 0.f;
    for (int p = 0; p < Pp; p++) sum += w2[t * Pp + p];
    sred[t] = sqrtf(sum * (1.0f / Pp));
  }
  __syncthreads();
  if (t == 0) {
    float a = 0.f;
    for (int i = 0; i < Bb * Cc; i++) a += sred[i];
    out[0] = a * (1.0f / (Bb * Cc));
  }
}

extern "C" void kernel_launch(void* const* d_in, const int* in_sizes, int n_in,
                              void* d_out, int out_size, void* d_ws, size_t ws_size,
                              hipStream_t stream) {
  const float* x    = (const float*)d_in[0];
  const float* y    = (const float*)d_in[1];
  const float* proj = (const float*)d_in[2];
  float* w2  = (float*)d_ws;                       // first 8KB of scratch
  float* xs  = (float*)((char*)d_ws + W2_BYTES);   // sorted-X staging
  float* out = (float*)d_out;

  const size_t lds = (size_t)LDS_FLOATS * sizeof(float);  // 132 KB
  (void)hipFuncSetAttribute((const void*)swd_fused,
                            hipFuncAttributeMaxDynamicSharedMemorySize, (int)lds);

  const size_t slice_bytes = (size_t)Nn * sizeof(float);
  const size_t avail = ws_size > W2_BYTES ? ws_size - W2_BYTES : 0;
  int chunk = (int)(avail / slice_bytes);
  if (chunk > SLICES) chunk = SLICES;
  if (chunk < 1) chunk = 1;

  for (int base = 0; base < SLICES; base += chunk) {
    int n = SLICES - base < chunk ? SLICES - base : chunk;
    hipLaunchKernelGGL(swd_fused, dim3(n), dim3(THREADS), lds, stream,
                       x, y, proj, xs, w2, base);
  }
  hipLaunchKernelGGL(swd_final, dim3(1), dim3(64), 0, stream, w2, out);
}

// Round 13
// 1041.557 us; speedup vs baseline: 1.2118x; 1.2118x over previous
//
#include <hip/hip_runtime.h>
#include <math.h>

// Sliced Wasserstein-2: for each (b,c,p): W2^2 = mean_i (sort(X@theta_p) - sort(Y@theta_p))^2
// loss = mean_{b,c} sqrt(mean_p W2^2)
//
// R13: revert fusion (R11: 371MB spill, R12 phase-loop: 937MB spill — any
// extra state around the sort tips the hard 64-VGPR budget into scratch).
// Base = R10 two-kernel split (proven VGPR=52, zero spill) + R11's
// merge_high3 three-layout top merges (a=13..15 fully in-register via
// L0 (reg=rank[4:0]) -> L2 (reg=rank[14:10]) -> L3 (reg=rank[9:5]);
// 192 conflict-free DS ops/merge vs 224 with bpermute stages, and no
// bpermute latency chains).

namespace {
constexpr int Bb = 8, Cc = 4, Nn = 32768, Pp = 50;
constexpr int THREADS = 1024;
constexpr int VPT = 32;                    // values per thread
constexpr int SLICES = Bb * Cc * Pp;       // 1600
constexpr size_t W2_BYTES = 8192;          // w2[1600] rounded up
constexpr int LDS_FLOATS = Nn + (Nn >> 5); // padded buffer: 33792 floats
}

__device__ __forceinline__ void ce(float& a, float& b, bool up) {
  float lo = fminf(a, b);
  float hi = fmaxf(a, b);
  a = up ? lo : hi;
  b = up ? hi : lo;
}

// 2-VALU compare-select CE: keepMin ? min(v,o) : max(v,o); ties resolve
// consistently on both partners (multiset preserved).
__device__ __forceinline__ float sel_ce(float v, float o, bool keepMin) {
  return ((o < v) != keepMin) ? v : o;
}

__device__ __forceinline__ float dpp_xor(float x, int ctrl_sel) {
  // 0xB1 = quad_perm(1,0,3,2) = xor1; 0x4E = quad_perm(2,3,0,1) = xor2
  int i = ctrl_sel == 0xB1
    ? __builtin_amdgcn_update_dpp(0, __float_as_int(x), 0xB1, 0xF, 0xF, true)
    : __builtin_amdgcn_update_dpp(0, __float_as_int(x), 0x4E, 0xF, 0xF, true);
  return __int_as_float(i);
}

// cross-lane CE stage with xor-mask M (M=1,2 via DPP; M>=4 via ds_bpermute)
template<int M>
__device__ __forceinline__ void stage_xlane(float v[VPT], int tid, bool up) {
  const bool keepMin = (up == ((tid & M) == 0));
  if constexpr (M == 1 || M == 2) {
    constexpr int ctrl = (M == 1) ? 0xB1 : 0x4E;
#pragma unroll
    for (int r = 0; r < VPT; r++) {
      float o = dpp_xor(v[r], ctrl);
      v[r] = sel_ce(v[r], o, keepMin);
    }
  } else {
    const int addr = (((tid & 63) ^ M) << 2);
#pragma unroll
    for (int r = 0; r < VPT; r++) {
      float o = __int_as_float(
          __builtin_amdgcn_ds_bpermute(addr, __float_as_int(v[r])));
      v[r] = sel_ce(v[r], o, keepMin);
    }
  }
}

// 5-stage in-register network on the reg-index bits (j=16..1), direction
// uniform per thread via sign-flip trick.
__device__ __forceinline__ void tail_inreg(float v[VPT], bool up) {
  const unsigned flip = up ? 0u : 0x80000000u;
#pragma unroll
  for (int r = 0; r < VPT; r++)
    v[r] = __int_as_float(__float_as_int(v[r]) ^ flip);
#pragma unroll
  for (int j = 16; j > 0; j >>= 1) {
#pragma unroll
    for (int r = 0; r < VPT; r++) {
      if (!(r & j)) {
        float a = v[r], b = v[r | j];
        v[r] = fminf(a, b);
        v[r | j] = fmaxf(a, b);
      }
    }
  }
#pragma unroll
  for (int r = 0; r < VPT; r++)
    v[r] = __int_as_float(__float_as_int(v[r]) ^ flip);
}

// wave-local cross stages (m = MTOP..1) + tail, for merge k = 2^A (A<=12)
template<int A, int MTOP>
__device__ __forceinline__ void wave_stages_and_tail(float v[VPT], int tid) {
  const bool up = ((tid & (1 << (A - 5))) == 0);
  if constexpr (MTOP >= 32) stage_xlane<32>(v, tid, up);
  if constexpr (MTOP >= 16) stage_xlane<16>(v, tid, up);
  if constexpr (MTOP >= 8)  stage_xlane<8>(v, tid, up);
  if constexpr (MTOP >= 4)  stage_xlane<4>(v, tid, up);
  if constexpr (MTOP >= 2)  stage_xlane<2>(v, tid, up);
  if constexpr (MTOP >= 1)  stage_xlane<1>(v, tid, up);
  tail_inreg(v, up);
}

// LDS-exchange stage (wave-crossing xor-mask m on tid), column layout
__device__ __forceinline__ void stage_lds(float v[VPT], float* s, int tid,
                                          int m, bool up) {
  const bool keepMin = (up == ((tid & m) == 0));
  __syncthreads();                        // prior users of s must finish
#pragma unroll
  for (int r = 0; r < VPT; r++) s[r * THREADS + tid] = v[r];
  __syncthreads();
  const int pt = tid ^ m;
#pragma unroll
  for (int r = 0; r < VPT; r++) {
    float o = s[r * THREADS + pt];
    v[r] = sel_ce(v[r], o, keepMin);
  }
}

// Merge k=2^A (A=13..15) entirely in-register via three layouts:
//  L0: i = tid<<5 | r        (reg = i[4:0])
//  L2: i = r2<<10 | tid      (reg = i[14:10]) -> stages b(A-1)..b10
//  L3: i = tid[9:5]<<10 | r3<<5 | tid[4:0] (reg = i[9:5]) -> stages b9..b5
// Caller finishes with tail_inreg in L0 (stages b4..b0).
// Padded addressing Adr(i) = i + (i>>5): every access <=2-way (free).
template<int A>
__device__ __forceinline__ void merge_high3(float v[VPT], float* s, int tid) {
  const int base = tid * VPT;
  // ---- L0 -> L2 ----
  __syncthreads();                      // prior users of s must finish
#pragma unroll
  for (int r = 0; r < VPT; r++) { int i = base + r; s[i + (i >> 5)] = v[r]; }
  __syncthreads();
#pragma unroll
  for (int r2 = 0; r2 < VPT; r2++) { int i = (r2 << 10) | tid; v[r2] = s[i + (i >> 5)]; }
  // ---- stages b(A-1)..b10 on reg bits, compile-time directions ----
#pragma unroll
  for (int bb = A - 11; bb >= 0; bb--) {
    const int j = 1 << bb;
#pragma unroll
    for (int r2 = 0; r2 < VPT; r2++) {
      if (!(r2 & j)) {
        bool upv = (A == 15) ? true : (((r2 >> (A - 10)) & 1) == 0);
        ce(v[r2], v[r2 | j], upv);
      }
    }
  }
  // ---- L2 -> L3 (rewrite own L2 slots: no barrier before write) ----
#pragma unroll
  for (int r2 = 0; r2 < VPT; r2++) { int i = (r2 << 10) | tid; s[i + (i >> 5)] = v[r2]; }
  __syncthreads();
  const int hi = (tid >> 5) << 10;      // tid[9:5] -> i[14:10]
  const int lo = tid & 31;              // tid[4:0] -> i[4:0]
#pragma unroll
  for (int r3 = 0; r3 < VPT; r3++) { int i = hi | (r3 << 5) | lo; v[r3] = s[i + (i >> 5)]; }
  // ---- stages b9..b5: direction = bit A of i = tid bit (A-5), thread-uniform ----
  const bool up = (A == 15) ? true : ((tid & (1 << (A - 5))) == 0);
  tail_inreg(v, up);
  // ---- L3 -> L0 (rewrite own L3 slots: no barrier before write) ----
#pragma unroll
  for (int r3 = 0; r3 < VPT; r3++) { int i = hi | (r3 << 5) | lo; s[i + (i >> 5)] = v[r3]; }
  __syncthreads();
#pragma unroll
  for (int r = 0; r < VPT; r++) { int i = base + r; v[r] = s[i + (i >> 5)]; }
}

// Full distributed bitonic sort: rank of v[r] on thread tid is tid*32 + r.
__device__ __forceinline__ void sort_dist(float v[VPT], float* s, int tid) {
  // merges a=1..4 (k=2..16): in-register, compile-time directions
#pragma unroll
  for (int k = 2; k <= 16; k <<= 1) {
#pragma unroll
    for (int j = k >> 1; j > 0; j >>= 1) {
#pragma unroll
      for (int r = 0; r < VPT; r++)
        if (!(r & j)) ce(v[r], v[r | j], (r & k) == 0);
    }
  }
  // a=5 (k=32): dir = tid bit0, all stages in-register
  tail_inreg(v, (tid & 1) == 0);
  // a=6..11: wave-local exchanges + tail
  wave_stages_and_tail<6, 1>(v, tid);
  wave_stages_and_tail<7, 2>(v, tid);
  wave_stages_and_tail<8, 4>(v, tid);
  wave_stages_and_tail<9, 8>(v, tid);
  wave_stages_and_tail<10, 16>(v, tid);
  wave_stages_and_tail<11, 32>(v, tid);
  // a=12: one wave-crossing stage (m=64), then wave-local
  stage_lds(v, s, tid, 64, (tid & 128) == 0);
  wave_stages_and_tail<12, 32>(v, tid);
  // a=13..15: three-layout merges (all stages in-register) + L0 tail
  merge_high3<13>(v, s, tid);
  tail_inreg(v, (tid & 256) == 0);
  merge_high3<14>(v, s, tid);
  tail_inreg(v, (tid & 512) == 0);
  merge_high3<15>(v, s, tid);
  tail_inreg(v, true);
}

__device__ __forceinline__ void project_slice(const float4* base, float t0, float t1,
                                              int tid, float v[VPT]) {
#pragma unroll
  for (int q = 0; q < VPT / 2; q++) {
    float4 u = base[tid * (VPT / 2) + q];
    v[2 * q]     = fmaf(u.x, t0, u.y * t1);
    v[2 * q + 1] = fmaf(u.z, t0, u.w * t1);
  }
}

// ---- kernel A: sort X slice, stage sorted run in scratch ----
extern "C" __global__ void __launch_bounds__(THREADS)
swd_sortx(const float* __restrict__ x, const float* __restrict__ proj,
          float* __restrict__ xs, int slice_base) {
  extern __shared__ float s[];
  const int slice = slice_base + blockIdx.x;
  const int p  = slice % Pp;
  const int bc = slice / Pp;
  const int tid = threadIdx.x;
  const float t0 = proj[2 * p];
  const float t1 = proj[2 * p + 1];
  float v[VPT];
  project_slice((const float4*)(x + (size_t)bc * Nn * 2), t0, t1, tid, v);
  sort_dist(v, s, tid);
  float4* o = (float4*)(xs + (size_t)blockIdx.x * Nn + tid * VPT);
#pragma unroll
  for (int q = 0; q < VPT / 4; q++)
    o[q] = make_float4(v[4 * q], v[4 * q + 1], v[4 * q + 2], v[4 * q + 3]);
}

// ---- kernel B: sort Y slice, diff against staged sorted X, reduce ----
extern "C" __global__ void __launch_bounds__(THREADS)
swd_sorty(const float* __restrict__ y, const float* __restrict__ proj,
          const float* __restrict__ xs, float* __restrict__ w2, int slice_base) {
  extern __shared__ float s[];
  __shared__ float wsum[THREADS / 64];
  const int slice = slice_base + blockIdx.x;
  const int p  = slice % Pp;
  const int bc = slice / Pp;
  const int tid = threadIdx.x;
  const float t0 = proj[2 * p];
  const float t1 = proj[2 * p + 1];
  float v[VPT];
  project_slice((const float4*)(y + (size_t)bc * Nn * 2), t0, t1, tid, v);
  sort_dist(v, s, tid);

  const float4* xr = (const float4*)(xs + (size_t)blockIdx.x * Nn + tid * VPT);
  float acc = 0.f;
#pragma unroll
  for (int q = 0; q < VPT / 4; q++) {
    float4 u = xr[q];
    float d0 = u.x - v[4 * q];
    float d1 = u.y - v[4 * q + 1];
    float d2 = u.z - v[4 * q + 2];
    float d3 = u.w - v[4 * q + 3];
    acc = fmaf(d0, d0, acc);
    acc = fmaf(d1, d1, acc);
    acc = fmaf(d2, d2, acc);
    acc = fmaf(d3, d3, acc);
  }
#pragma unroll
  for (int off = 32; off > 0; off >>= 1)
    acc += __shfl_down(acc, off, 64);
  if ((tid & 63) == 0) wsum[tid >> 6] = acc;
  __syncthreads();
  if (tid == 0) {
    float t = 0.f;
#pragma unroll
    for (int w = 0; w < THREADS / 64; w++) t += wsum[w];
    w2[slice] = t * (1.0f / Nn);
  }
}

extern "C" __global__ void swd_final(const float* __restrict__ w2,
                                     float* __restrict__ out) {
  __shared__ float sred[Bb * Cc];
  int t = threadIdx.x;
  if (t < Bb * Cc) {
    float sum = 0.f;
    for (int p = 0; p < Pp; p++) sum += w2[t * Pp + p];
    sred[t] = sqrtf(sum * (1.0f / Pp));
  }
  __syncthreads();
  if (t == 0) {
    float a = 0.f;
    for (int i = 0; i < Bb * Cc; i++) a += sred[i];
    out[0] = a * (1.0f / (Bb * Cc));
  }
}

extern "C" void kernel_launch(void* const* d_in, const int* in_sizes, int n_in,
                              void* d_out, int out_size, void* d_ws, size_t ws_size,
                              hipStream_t stream) {
  const float* x    = (const float*)d_in[0];
  const float* y    = (const float*)d_in[1];
  const float* proj = (const float*)d_in[2];
  float* w2  = (float*)d_ws;                       // first 8KB of scratch
  float* xs  = (float*)((char*)d_ws + W2_BYTES);   // sorted-X staging
  float* out = (float*)d_out;

  const size_t lds = (size_t)LDS_FLOATS * sizeof(float);  // 132 KB
  (void)hipFuncSetAttribute((const void*)swd_sortx,
                            hipFuncAttributeMaxDynamicSharedMemorySize, (int)lds);
  (void)hipFuncSetAttribute((const void*)swd_sorty,
                            hipFuncAttributeMaxDynamicSharedMemorySize, (int)lds);

  const size_t slice_bytes = (size_t)Nn * sizeof(float);
  const size_t avail = ws_size > W2_BYTES ? ws_size - W2_BYTES : 0;
  int chunk = (int)(avail / slice_bytes);
  if (chunk > SLICES) chunk = SLICES;
  if (chunk < 1) chunk = 1;

  for (int base = 0; base < SLICES; base += chunk) {
    int n = SLICES - base < chunk ? SLICES - base : chunk;
    hipLaunchKernelGGL(swd_sortx, dim3(n), dim3(THREADS), lds, stream,
                       x, proj, xs, base);
    hipLaunchKernelGGL(swd_sorty, dim3(n), dim3(THREADS), lds, stream,
                       y, proj, xs, w2, base);
  }
  hipLaunchKernelGGL(swd_final, dim3(1), dim3(64), 0, stream, w2, out);
}